// Round 1
// baseline (125636.426 us; speedup 1.0000x reference)
//
#include <hip/hip_runtime.h>
#include <hip/hip_cooperative_groups.h>
#include <math.h>

namespace cg = cooperative_groups;

#define H        4096
#define H4       (H / 4)
#define SEQ      2048
#define HOR      64
#define NBLK     256
#define NTHR     1024
#define NWAVE    (NTHR / 64)
#define CHUNK    NWAVE      // h rows per block (one per wave)

__device__ __forceinline__ float wave_reduce(float v) {
#pragma unroll
    for (int o = 32; o > 0; o >>= 1) v += __shfl_xor(v, o, 64);
    return v;
}

// Persistent cooperative GRU kernel.
// Geometry: 256 blocks x 1024 threads = 1 block/CU, 16 waves/block.
// Wave w of block b owns h-index hi = b*16 + w and computes the three
// row-dots (u_Wh[hi,:], r_Wh[hi,:], Wh[hi,:]) against h staged in LDS.
// One grid.sync() per timestep; h ping-pongs between ws[0:H] and ws[H:2H].
__global__ __launch_bounds__(NTHR) void gru_kernel(
    const float* __restrict__ xseq,
    const float* __restrict__ uWx, const float* __restrict__ uWh, const float* __restrict__ ubv,
    const float* __restrict__ rWx, const float* __restrict__ rWh, const float* __restrict__ rbv,
    const float* __restrict__ wxv, const float* __restrict__ Whm, const float* __restrict__ bbv,
    const float* __restrict__ Vv,  const float* __restrict__ cv,
    float* __restrict__ out, float* __restrict__ ws)
{
    cg::grid_group grid = cg::this_grid();
    __shared__ float4 h_lds[H4];   // full h vector, 16 KiB
    __shared__ float  red[NWAVE];

    const int tid  = threadIdx.x;
    const int wave = tid >> 6;
    const int lane = tid & 63;
    const int hi   = blockIdx.x * CHUNK + wave;

    float* hA = ws;        // h for even t
    float* hB = ws + H;    // h for odd t

    // h0 = 0 (d_ws is poisoned 0xAA before every launch)
    if (blockIdx.x == 0) {
        ((float4*)hA)[tid] = make_float4(0.f, 0.f, 0.f, 0.f);
    }

    const float c0 = cv[0];
    const float4* __restrict__ urow = (const float4*)(uWh + (size_t)hi * H);
    const float4* __restrict__ rrow = (const float4*)(rWh + (size_t)hi * H);
    const float4* __restrict__ wrow = (const float4*)(Whm + (size_t)hi * H);
    const float uwx_i = uWx[hi], ub_i = ubv[hi];
    const float rwx_i = rWx[hi], rb_i = rbv[hi];
    const float wx_i  = wxv[hi], bb_i = bbv[hi];

    grid.sync();

    for (int t = 0; t < SEQ + HOR; ++t) {
        const float4* hin  = (const float4*)((t & 1) ? hB : hA);
        float*        hout = (t & 1) ? hA : hB;

        // stage h_t into LDS (1024 threads x 1 float4 = full vector)
        h_lds[tid] = hin[tid];
        __syncthreads();

        float x;
        if (t < SEQ) {
            x = xseq[t];            // broadcast load, cache-served
        } else {
            // y_t = v . h_t + c0, computed redundantly (and identically) in
            // every block from LDS -> deterministic, no atomics, no extra sync.
            float4 hv = h_lds[tid];
            float4 vv = ((const float4*)Vv)[tid];
            float p = hv.x * vv.x + hv.y * vv.y + hv.z * vv.z + hv.w * vv.w;
            p = wave_reduce(p);
            if (lane == 0) red[wave] = p;
            __syncthreads();
            float y = c0;
#pragma unroll
            for (int w = 0; w < NWAVE; ++w) y += red[w];
            x = y;                   // AR input
            // y at step t corresponds to h_t = h_new of step t-1:
            // t = SEQ       -> y_last (not an output)
            // t = SEQ+1+k   -> preds[k], k = 0..62  (preds[63] after the loop)
            if (t > SEQ && blockIdx.x == 0 && tid == 0) out[t - SEQ - 1] = y;
        }

        // three row-dots against LDS-resident h (h read once, used 3x)
        float au = 0.f, ar = 0.f, aw = 0.f;
        for (int k = lane; k < H4; k += 64) {
            const float4 hv = h_lds[k];
            const float4 a = urow[k];
            const float4 b = rrow[k];
            const float4 w = wrow[k];
            au = fmaf(a.x, hv.x, au); au = fmaf(a.y, hv.y, au);
            au = fmaf(a.z, hv.z, au); au = fmaf(a.w, hv.w, au);
            ar = fmaf(b.x, hv.x, ar); ar = fmaf(b.y, hv.y, ar);
            ar = fmaf(b.z, hv.z, ar); ar = fmaf(b.w, hv.w, ar);
            aw = fmaf(w.x, hv.x, aw); aw = fmaf(w.y, hv.y, aw);
            aw = fmaf(w.z, hv.z, aw); aw = fmaf(w.w, hv.w, aw);
        }
        au = wave_reduce(au);
        ar = wave_reduce(ar);
        aw = wave_reduce(aw);

        if (lane == 0) {
            const float h_old = ((const float*)h_lds)[hi];
            const float zu = fmaf(uwx_i, x, au + ub_i);
            const float zr = fmaf(rwx_i, x, ar + rb_i);
            const float u  = 1.f / (1.f + expf(-zu));
            const float r  = 1.f / (1.f + expf(-zr));
            const float hh = tanhf(fmaf(wx_i, x, fmaf(r, aw, bb_i)));
            hout[hi] = fmaf(u, hh - h_old, h_old);   // (1-u)*h + u*hh
        }
        grid.sync();
    }

    // preds[63] = v . h_final + c0  (h_final is in hA: SEQ+HOR is even)
    if (blockIdx.x == 0) {
        float4 hv = ((const float4*)hA)[tid];
        float4 vv = ((const float4*)Vv)[tid];
        float p = hv.x * vv.x + hv.y * vv.y + hv.z * vv.z + hv.w * vv.w;
        p = wave_reduce(p);
        if (lane == 0) red[wave] = p;
        __syncthreads();
        if (tid == 0) {
            float y = c0;
            for (int w = 0; w < NWAVE; ++w) y += red[w];
            out[HOR - 1] = y;
        }
    }
}

extern "C" void kernel_launch(void* const* d_in, const int* in_sizes, int n_in,
                              void* d_out, int out_size, void* d_ws, size_t ws_size,
                              hipStream_t stream) {
    // setup_inputs order:
    // 0: input_sequence (2048 f32)   1: horizon (int, =64)
    // 2: u_Wx  3: u_Wh  4: u_b  5: r_Wx  6: r_Wh  7: r_b
    // 8: Wx    9: Wh   10: b   11: V    12: c
    const float* xseq = (const float*)d_in[0];
    const float* uWx  = (const float*)d_in[2];
    const float* uWh  = (const float*)d_in[3];
    const float* ubv  = (const float*)d_in[4];
    const float* rWx  = (const float*)d_in[5];
    const float* rWh  = (const float*)d_in[6];
    const float* rbv  = (const float*)d_in[7];
    const float* wxv  = (const float*)d_in[8];
    const float* Whm  = (const float*)d_in[9];
    const float* bbv  = (const float*)d_in[10];
    const float* Vv   = (const float*)d_in[11];
    const float* cv   = (const float*)d_in[12];
    float* out = (float*)d_out;
    float* ws  = (float*)d_ws;

    void* args[] = { &xseq, &uWx, &uWh, &ubv, &rWx, &rWh, &rbv,
                     &wxv, &Whm, &bbv, &Vv, &cv, &out, &ws };
    hipLaunchCooperativeKernel((void*)gru_kernel, dim3(NBLK), dim3(NTHR),
                               args, 0, stream);
}

// Round 2
// 78365.057 us; speedup vs baseline: 1.6032x; 1.6032x over previous
//
#include <hip/hip_runtime.h>
#include <hip/hip_cooperative_groups.h>
#include <hip/hip_fp16.h>
#include <math.h>

namespace cg = cooperative_groups;

#define H      4096
#define SEQ    2048
#define HOR    64
#define NBLK   256
#define NTHR   512
#define NWAVE  (NTHR / 64)
#define RPW    2            // rows per wave; 8 waves * 2 = 16 rows per block
#define J      16           // float4 chunks per lane per row: H/(64*4)

#define SMEM_H     (H * 4)              // 16384 B: h vector (fp32)
#define SMEM_R     (NWAVE * RPW * H * 2) // 131072 B: r_Wh rows (fp16)
#define SMEM_RED   64
#define SMEM_BYTES (SMEM_H + SMEM_R + SMEM_RED)

__device__ __forceinline__ float wave_reduce(float v) {
#pragma unroll
    for (int o = 32; o > 0; o >>= 1) v += __shfl_xor(v, o, 64);
    return v;
}

__device__ __forceinline__ float dot4(float4 a, float4 b) {
    float s = a.x * b.x;
    s = fmaf(a.y, b.y, s);
    s = fmaf(a.z, b.z, s);
    s = fmaf(a.w, b.w, s);
    return s;
}

union H4U { uint2 u; __half h[4]; };

__device__ __forceinline__ uint2 pack4(float4 v) {
    H4U c;
    c.h[0] = __float2half_rn(v.x); c.h[1] = __float2half_rn(v.y);
    c.h[2] = __float2half_rn(v.z); c.h[3] = __float2half_rn(v.w);
    return c.u;
}

__device__ __forceinline__ float4 unpack4(uint2 p) {
    H4U c; c.u = p;
    return make_float4(__half2float(c.h[0]), __half2float(c.h[1]),
                       __half2float(c.h[2]), __half2float(c.h[3]));
}

// Fully weight-resident persistent GRU.
// 256 blocks x 512 threads, 1 block/CU. Block b owns rows [16b, 16b+16);
// wave w owns rows r0=16b+2w, r1=r0+1.
// Residency per CU: Wh rows fp32 in VGPRs (128/wave), u_Wh rows fp16 in
// VGPRs (64/wave), r_Wh rows fp16 in LDS (128 KB), h staged in LDS (16 KB).
// Steady state reads NO weight bytes from memory.
__global__ __launch_bounds__(NTHR, 2) void gru_kernel(
    const float* __restrict__ xseq,
    const float* __restrict__ uWx, const float* __restrict__ uWh, const float* __restrict__ ubv,
    const float* __restrict__ rWx, const float* __restrict__ rWh, const float* __restrict__ rbv,
    const float* __restrict__ wxv, const float* __restrict__ Whm, const float* __restrict__ bbv,
    const float* __restrict__ Vv,  const float* __restrict__ cv,
    float* __restrict__ out, float* __restrict__ ws)
{
    cg::grid_group grid = cg::this_grid();
    extern __shared__ unsigned char smem[];
    float* hF  = (float*)smem;                         // h, 4096 fp32
    uint2* rW  = (uint2*)(smem + SMEM_H);              // r_Wh fp16, 16 rows x 1024 uint2
    float* red = (float*)(smem + SMEM_H + SMEM_R);     // NWAVE partials

    const int tid  = threadIdx.x;
    const int wv   = tid >> 6;
    const int lane = tid & 63;
    const int bid  = blockIdx.x;
    const int r0   = bid * (NWAVE * RPW) + wv * RPW;
    const int r1   = r0 + 1;

    float* hA = ws;
    float* hB = ws + H;

    // ---- one-time load: pin weights on-chip ----
    const float4* w0p = (const float4*)(Whm + (size_t)r0 * H);
    const float4* w1p = (const float4*)(Whm + (size_t)r1 * H);
    const float4* u0p = (const float4*)(uWh + (size_t)r0 * H);
    const float4* u1p = (const float4*)(uWh + (size_t)r1 * H);
    const float4* p0p = (const float4*)(rWh + (size_t)r0 * H);
    const float4* p1p = (const float4*)(rWh + (size_t)r1 * H);

    float4 wA[J], wB[J];
    uint2  uA[J], uB[J];
    uint2* rs0 = rW + (wv * RPW + 0) * (H / 4);
    uint2* rs1 = rW + (wv * RPW + 1) * (H / 4);

#pragma unroll
    for (int j = 0; j < J; ++j) {
        const int idx = j * 64 + lane;
        wA[j] = w0p[idx];
        wB[j] = w1p[idx];
        uA[j] = pack4(u0p[idx]);
        uB[j] = pack4(u1p[idx]);
        rs0[idx] = pack4(p0p[idx]);
        rs1[idx] = pack4(p1p[idx]);
    }
    // Opaque pins: forbid rematerialization of the resident weights.
#pragma unroll
    for (int j = 0; j < J; ++j) {
        asm volatile("" : "+v"(wA[j].x), "+v"(wA[j].y), "+v"(wA[j].z), "+v"(wA[j].w));
        asm volatile("" : "+v"(wB[j].x), "+v"(wB[j].y), "+v"(wB[j].z), "+v"(wB[j].w));
        asm volatile("" : "+v"(uA[j].x), "+v"(uA[j].y));
        asm volatile("" : "+v"(uB[j].x), "+v"(uB[j].y));
    }

    // per-row gate constants
    const float uwx0 = uWx[r0], uwx1 = uWx[r1], ub0 = ubv[r0], ub1 = ubv[r1];
    const float rwx0 = rWx[r0], rwx1 = rWx[r1], rb0 = rbv[r0], rb1 = rbv[r1];
    const float wx0  = wxv[r0], wx1  = wxv[r1], bb0 = bbv[r0], bb1 = bbv[r1];
    const float c0 = cv[0];

    // h0 = 0: each block zeroes its own 16 entries of hA
    if (tid < NWAVE * RPW) hA[bid * (NWAVE * RPW) + tid] = 0.f;

    grid.sync();

    const float4* v4g = (const float4*)Vv;

#pragma unroll 1
    for (int t = 0; t < SEQ + HOR; ++t) {
        const float4* hin4 = (const float4*)((t & 1) ? hB : hA);
        float*        hout = (t & 1) ? hA : hB;

        // stage h into LDS (512 threads x 2 float4 = 16 KB)
        ((float4*)hF)[tid]        = hin4[tid];
        ((float4*)hF)[tid + NTHR] = hin4[tid + NTHR];
        __syncthreads();

        float x;
        if (t < SEQ) {
            x = xseq[t];
        } else {
            // y = v.h + c0, redundantly and identically in every block
            float4 a0 = ((const float4*)hF)[tid];
            float4 a1 = ((const float4*)hF)[tid + NTHR];
            float p = dot4(a0, v4g[tid]) + dot4(a1, v4g[tid + NTHR]);
            p = wave_reduce(p);
            if (lane == 0) red[wv] = p;
            __syncthreads();
            float y = c0;
#pragma unroll
            for (int w = 0; w < NWAVE; ++w) y += red[w];
            x = y;
            if (t > SEQ && bid == 0 && tid == 0) out[t - SEQ - 1] = y;
        }

        // six resident row-dots against LDS h
        float au0 = 0.f, au1 = 0.f, ar0 = 0.f, ar1 = 0.f, aw0 = 0.f, aw1 = 0.f;
#pragma unroll
        for (int j = 0; j < J; ++j) {
            const int idx = j * 64 + lane;
            const float4 hv = ((const float4*)hF)[idx];
            aw0 = fmaf(wA[j].x, hv.x, aw0); aw0 = fmaf(wA[j].y, hv.y, aw0);
            aw0 = fmaf(wA[j].z, hv.z, aw0); aw0 = fmaf(wA[j].w, hv.w, aw0);
            aw1 = fmaf(wB[j].x, hv.x, aw1); aw1 = fmaf(wB[j].y, hv.y, aw1);
            aw1 = fmaf(wB[j].z, hv.z, aw1); aw1 = fmaf(wB[j].w, hv.w, aw1);
            const float4 ua = unpack4(uA[j]);
            au0 = fmaf(ua.x, hv.x, au0); au0 = fmaf(ua.y, hv.y, au0);
            au0 = fmaf(ua.z, hv.z, au0); au0 = fmaf(ua.w, hv.w, au0);
            const float4 ub = unpack4(uB[j]);
            au1 = fmaf(ub.x, hv.x, au1); au1 = fmaf(ub.y, hv.y, au1);
            au1 = fmaf(ub.z, hv.z, au1); au1 = fmaf(ub.w, hv.w, au1);
            const float4 ra = unpack4(rs0[idx]);
            ar0 = fmaf(ra.x, hv.x, ar0); ar0 = fmaf(ra.y, hv.y, ar0);
            ar0 = fmaf(ra.z, hv.z, ar0); ar0 = fmaf(ra.w, hv.w, ar0);
            const float4 rb = unpack4(rs1[idx]);
            ar1 = fmaf(rb.x, hv.x, ar1); ar1 = fmaf(rb.y, hv.y, ar1);
            ar1 = fmaf(rb.z, hv.z, ar1); ar1 = fmaf(rb.w, hv.w, ar1);
        }
        au0 = wave_reduce(au0); au1 = wave_reduce(au1);
        ar0 = wave_reduce(ar0); ar1 = wave_reduce(ar1);
        aw0 = wave_reduce(aw0); aw1 = wave_reduce(aw1);

        if (lane == 0) {
            const float ho0 = hF[r0], ho1 = hF[r1];
            const float zu0 = fmaf(uwx0, x, au0 + ub0);
            const float zr0 = fmaf(rwx0, x, ar0 + rb0);
            const float u0  = 1.f / (1.f + expf(-zu0));
            const float g0  = 1.f / (1.f + expf(-zr0));
            const float hh0 = tanhf(fmaf(wx0, x, fmaf(g0, aw0, bb0)));
            hout[r0] = fmaf(u0, hh0 - ho0, ho0);
            const float zu1 = fmaf(uwx1, x, au1 + ub1);
            const float zr1 = fmaf(rwx1, x, ar1 + rb1);
            const float u1  = 1.f / (1.f + expf(-zu1));
            const float g1  = 1.f / (1.f + expf(-zr1));
            const float hh1 = tanhf(fmaf(wx1, x, fmaf(g1, aw1, bb1)));
            hout[r1] = fmaf(u1, hh1 - ho1, ho1);
        }
        grid.sync();
    }

    // preds[63] from final h (SEQ+HOR even -> hA)
    if (bid == 0) {
        const float4* hf4 = (const float4*)hA;
        float p = dot4(hf4[tid], v4g[tid]) + dot4(hf4[tid + NTHR], v4g[tid + NTHR]);
        p = wave_reduce(p);
        if (lane == 0) red[wv] = p;
        __syncthreads();
        if (tid == 0) {
            float y = c0;
            for (int w = 0; w < NWAVE; ++w) y += red[w];
            out[HOR - 1] = y;
        }
    }
}

extern "C" void kernel_launch(void* const* d_in, const int* in_sizes, int n_in,
                              void* d_out, int out_size, void* d_ws, size_t ws_size,
                              hipStream_t stream) {
    const float* xseq = (const float*)d_in[0];
    const float* uWx  = (const float*)d_in[2];
    const float* uWh  = (const float*)d_in[3];
    const float* ubv  = (const float*)d_in[4];
    const float* rWx  = (const float*)d_in[5];
    const float* rWh  = (const float*)d_in[6];
    const float* rbv  = (const float*)d_in[7];
    const float* wxv  = (const float*)d_in[8];
    const float* Whm  = (const float*)d_in[9];
    const float* bbv  = (const float*)d_in[10];
    const float* Vv   = (const float*)d_in[11];
    const float* cv   = (const float*)d_in[12];
    float* out = (float*)d_out;
    float* ws  = (float*)d_ws;

    static int attr_done = 0;
    (void)attr_done;
    hipFuncSetAttribute((const void*)gru_kernel,
                        hipFuncAttributeMaxDynamicSharedMemorySize, SMEM_BYTES);

    void* args[] = { &xseq, &uWx, &uWh, &ubv, &rWx, &rWh, &rbv,
                     &wxv, &Whm, &bbv, &Vv, &cv, &out, &ws };
    hipLaunchCooperativeKernel((void*)gru_kernel, dim3(NBLK), dim3(NTHR),
                               args, SMEM_BYTES, stream);
}

// Round 3
// 67882.593 us; speedup vs baseline: 1.8508x; 1.1544x over previous
//
#include <hip/hip_runtime.h>
#include <hip/hip_cooperative_groups.h>
#include <hip/hip_fp16.h>
#include <math.h>

namespace cg = cooperative_groups;

#define H      4096
#define SEQ    2048
#define HOR    64
#define NBLK   256
#define NTHR   512
#define NWAVE  (NTHR / 64)
#define RPW    2            // rows per wave; 8 waves * 2 = 16 rows per block
#define J      16           // float4 chunks per lane per row: H/(64*4)

#define SMEM_H     (H * 4)               // 16384 B: h vector (fp32)
#define SMEM_R     (NWAVE * RPW * H * 2) // 131072 B: r_Wh rows (fp16)
#define SMEM_RED   64
#define SMEM_BYTES (SMEM_H + SMEM_R + SMEM_RED)

#define AGENT __HIP_MEMORY_SCOPE_AGENT

__device__ __forceinline__ float wave_reduce(float v) {
#pragma unroll
    for (int o = 32; o > 0; o >>= 1) v += __shfl_xor(v, o, 64);
    return v;
}

__device__ __forceinline__ float dot4(float4 a, float4 b) {
    float s = a.x * b.x;
    s = fmaf(a.y, b.y, s);
    s = fmaf(a.z, b.z, s);
    s = fmaf(a.w, b.w, s);
    return s;
}

union H4U { uint2 u; __half h[4]; };

__device__ __forceinline__ uint2 pack4(float4 v) {
    H4U c;
    c.h[0] = __float2half_rn(v.x); c.h[1] = __float2half_rn(v.y);
    c.h[2] = __float2half_rn(v.z); c.h[3] = __float2half_rn(v.w);
    return c.u;
}

__device__ __forceinline__ float4 unpack4(uint2 p) {
    H4U c; c.u = p;
    return make_float4(__half2float(c.h[0]), __half2float(c.h[1]),
                       __half2float(c.h[2]), __half2float(c.h[3]));
}

// Fully weight-resident persistent GRU with a contention-free flag barrier.
// 256 blocks x 512 threads, 1 block/CU. Block b owns rows [16b, 16b+16).
// Residency: Wh fp32 + u_Wh fp16 in VGPRs/AGPRs, r_Wh fp16 in LDS (128 KB).
// Per step: device-scope h exchange (16 KB) + per-block flag release-store;
// 256 threads/block each poll ONE flag (no shared atomic counter -> no
// 256-way same-address atomic serialization like cg::grid.sync()).
__global__ __launch_bounds__(NTHR, 2) void gru_kernel(
    const float* __restrict__ xseq,
    const float* __restrict__ uWx, const float* __restrict__ uWh, const float* __restrict__ ubv,
    const float* __restrict__ rWx, const float* __restrict__ rWh, const float* __restrict__ rbv,
    const float* __restrict__ wxv, const float* __restrict__ Whm, const float* __restrict__ bbv,
    const float* __restrict__ Vv,  const float* __restrict__ cv,
    float* __restrict__ out, float* __restrict__ ws)
{
    cg::grid_group grid = cg::this_grid();
    extern __shared__ unsigned char smem[];
    float* hF  = (float*)smem;                         // h, 4096 fp32
    uint2* rW  = (uint2*)(smem + SMEM_H);              // r_Wh fp16
    float* red = (float*)(smem + SMEM_H + SMEM_R);     // NWAVE partials

    const int tid  = threadIdx.x;
    const int wv   = tid >> 6;
    const int lane = tid & 63;
    const int bid  = blockIdx.x;
    const int r0   = bid * (NWAVE * RPW) + wv * RPW;
    const int r1   = r0 + 1;

    float* hA = ws;
    float* hB = ws + H;
    int*   flags = (int*)(ws + 2 * H);   // poisoned 0xAAAAAAAA = negative int -> no init needed

    // ---- one-time load: pin weights on-chip ----
    const float4* w0p = (const float4*)(Whm + (size_t)r0 * H);
    const float4* w1p = (const float4*)(Whm + (size_t)r1 * H);
    const float4* u0p = (const float4*)(uWh + (size_t)r0 * H);
    const float4* u1p = (const float4*)(uWh + (size_t)r1 * H);
    const float4* p0p = (const float4*)(rWh + (size_t)r0 * H);
    const float4* p1p = (const float4*)(rWh + (size_t)r1 * H);

    float4 wA[J], wB[J];
    uint2  uA[J], uB[J];
    uint2* rs0 = rW + (wv * RPW + 0) * (H / 4);
    uint2* rs1 = rW + (wv * RPW + 1) * (H / 4);

#pragma unroll
    for (int j = 0; j < J; ++j) {
        const int idx = j * 64 + lane;
        wA[j] = w0p[idx];
        wB[j] = w1p[idx];
        uA[j] = pack4(u0p[idx]);
        uB[j] = pack4(u1p[idx]);
        rs0[idx] = pack4(p0p[idx]);
        rs1[idx] = pack4(p1p[idx]);
    }
#pragma unroll
    for (int j = 0; j < J; ++j) {
        asm volatile("" : "+v"(wA[j].x), "+v"(wA[j].y), "+v"(wA[j].z), "+v"(wA[j].w));
        asm volatile("" : "+v"(wB[j].x), "+v"(wB[j].y), "+v"(wB[j].z), "+v"(wB[j].w));
        asm volatile("" : "+v"(uA[j].x), "+v"(uA[j].y));
        asm volatile("" : "+v"(uB[j].x), "+v"(uB[j].y));
    }

    const float uwx0 = uWx[r0], uwx1 = uWx[r1], ub0 = ubv[r0], ub1 = ubv[r1];
    const float rwx0 = rWx[r0], rwx1 = rWx[r1], rb0 = rbv[r0], rb1 = rbv[r1];
    const float wx0  = wxv[r0], wx1  = wxv[r1], bb0 = bbv[r0], bb1 = bbv[r1];
    const float c0 = cv[0];

    // h0 = 0: each block zeroes its own 16 entries of hA
    if (tid < NWAVE * RPW) hA[bid * (NWAVE * RPW) + tid] = 0.f;

    grid.sync();   // one-time: publishes h0 zeros; flags stay poisoned (negative)

    const float4* v4g = (const float4*)Vv;

#pragma unroll 1
    for (int t = 0; t < SEQ + HOR; ++t) {
        // ---- fast grid barrier: wait until all blocks published h_t ----
        if (t > 0) {
            if (tid < NBLK) {
                while (__hip_atomic_load(&flags[tid], __ATOMIC_ACQUIRE, AGENT) < t)
                    __builtin_amdgcn_s_sleep(1);
            }
            __syncthreads();
        }

        // ---- stage h_t into LDS via device-scope loads (bypass stale caches) ----
        const unsigned long long* hin8 = (const unsigned long long*)((t & 1) ? hB : hA);
        float* hout = (t & 1) ? hA : hB;
        unsigned long long* hF8 = (unsigned long long*)hF;
#pragma unroll
        for (int k = 0; k < 4; ++k) {
            const int idx = k * NTHR + tid;   // coalesced: consecutive lanes, consecutive 8B
            hF8[idx] = __hip_atomic_load((unsigned long long*)&hin8[idx],
                                         __ATOMIC_RELAXED, AGENT);
        }
        __syncthreads();

        float x;
        if (t < SEQ) {
            x = xseq[t];
        } else {
            // y = v.h + c0, redundantly and identically in every block
            float4 a0 = ((const float4*)hF)[tid];
            float4 a1 = ((const float4*)hF)[tid + NTHR];
            float p = dot4(a0, v4g[tid]) + dot4(a1, v4g[tid + NTHR]);
            p = wave_reduce(p);
            if (lane == 0) red[wv] = p;
            __syncthreads();
            float y = c0;
#pragma unroll
            for (int w = 0; w < NWAVE; ++w) y += red[w];
            x = y;
            if (t > SEQ && bid == 0 && tid == 0) out[t - SEQ - 1] = y;
        }

        // ---- six resident row-dots against LDS h ----
        float au0 = 0.f, au1 = 0.f, ar0 = 0.f, ar1 = 0.f, aw0 = 0.f, aw1 = 0.f;
#pragma unroll
        for (int j = 0; j < J; ++j) {
            const int idx = j * 64 + lane;
            const float4 hv = ((const float4*)hF)[idx];
            aw0 = fmaf(wA[j].x, hv.x, aw0); aw0 = fmaf(wA[j].y, hv.y, aw0);
            aw0 = fmaf(wA[j].z, hv.z, aw0); aw0 = fmaf(wA[j].w, hv.w, aw0);
            aw1 = fmaf(wB[j].x, hv.x, aw1); aw1 = fmaf(wB[j].y, hv.y, aw1);
            aw1 = fmaf(wB[j].z, hv.z, aw1); aw1 = fmaf(wB[j].w, hv.w, aw1);
            const float4 ua = unpack4(uA[j]);
            au0 = fmaf(ua.x, hv.x, au0); au0 = fmaf(ua.y, hv.y, au0);
            au0 = fmaf(ua.z, hv.z, au0); au0 = fmaf(ua.w, hv.w, au0);
            const float4 ub = unpack4(uB[j]);
            au1 = fmaf(ub.x, hv.x, au1); au1 = fmaf(ub.y, hv.y, au1);
            au1 = fmaf(ub.z, hv.z, au1); au1 = fmaf(ub.w, hv.w, au1);
            const float4 ra = unpack4(rs0[idx]);
            ar0 = fmaf(ra.x, hv.x, ar0); ar0 = fmaf(ra.y, hv.y, ar0);
            ar0 = fmaf(ra.z, hv.z, ar0); ar0 = fmaf(ra.w, hv.w, ar0);
            const float4 rb = unpack4(rs1[idx]);
            ar1 = fmaf(rb.x, hv.x, ar1); ar1 = fmaf(rb.y, hv.y, ar1);
            ar1 = fmaf(rb.z, hv.z, ar1); ar1 = fmaf(rb.w, hv.w, ar1);
        }
        au0 = wave_reduce(au0); au1 = wave_reduce(au1);
        ar0 = wave_reduce(ar0); ar1 = wave_reduce(ar1);
        aw0 = wave_reduce(aw0); aw1 = wave_reduce(aw1);

        if (lane == 0) {
            const float ho0 = hF[r0], ho1 = hF[r1];
            const float zu0 = fmaf(uwx0, x, au0 + ub0);
            const float zr0 = fmaf(rwx0, x, ar0 + rb0);
            const float u0  = 1.f / (1.f + expf(-zu0));
            const float g0  = 1.f / (1.f + expf(-zr0));
            const float hh0 = tanhf(fmaf(wx0, x, fmaf(g0, aw0, bb0)));
            __hip_atomic_store(&hout[r0], fmaf(u0, hh0 - ho0, ho0),
                               __ATOMIC_RELAXED, AGENT);
            const float zu1 = fmaf(uwx1, x, au1 + ub1);
            const float zr1 = fmaf(rwx1, x, ar1 + rb1);
            const float u1  = 1.f / (1.f + expf(-zu1));
            const float g1  = 1.f / (1.f + expf(-zr1));
            const float hh1 = tanhf(fmaf(wx1, x, fmaf(g1, aw1, bb1)));
            __hip_atomic_store(&hout[r1], fmaf(u1, hh1 - ho1, ho1),
                               __ATOMIC_RELAXED, AGENT);
        }

        // publish: __syncthreads() drains all lane0 stores (vmcnt(0) before
        // s_barrier), then one release-store of this block's flag.
        __syncthreads();
        if (tid == 0)
            __hip_atomic_store(&flags[bid], t + 1, __ATOMIC_RELEASE, AGENT);
    }

    // preds[63] from final h (SEQ+HOR even -> hA); block 0 must see all blocks
    if (bid == 0) {
        if (tid < NBLK) {
            while (__hip_atomic_load(&flags[tid], __ATOMIC_ACQUIRE, AGENT) < SEQ + HOR)
                __builtin_amdgcn_s_sleep(1);
        }
        __syncthreads();
        const unsigned long long* hf8 = (const unsigned long long*)hA;
        unsigned long long* hF8 = (unsigned long long*)hF;
#pragma unroll
        for (int k = 0; k < 4; ++k) {
            const int idx = k * NTHR + tid;
            hF8[idx] = __hip_atomic_load((unsigned long long*)&hf8[idx],
                                         __ATOMIC_RELAXED, AGENT);
        }
        __syncthreads();
        float4 a0 = ((const float4*)hF)[tid];
        float4 a1 = ((const float4*)hF)[tid + NTHR];
        float p = dot4(a0, v4g[tid]) + dot4(a1, v4g[tid + NTHR]);
        p = wave_reduce(p);
        if (lane == 0) red[wv] = p;
        __syncthreads();
        if (tid == 0) {
            float y = c0;
            for (int w = 0; w < NWAVE; ++w) y += red[w];
            out[HOR - 1] = y;
        }
    }
}

extern "C" void kernel_launch(void* const* d_in, const int* in_sizes, int n_in,
                              void* d_out, int out_size, void* d_ws, size_t ws_size,
                              hipStream_t stream) {
    const float* xseq = (const float*)d_in[0];
    const float* uWx  = (const float*)d_in[2];
    const float* uWh  = (const float*)d_in[3];
    const float* ubv  = (const float*)d_in[4];
    const float* rWx  = (const float*)d_in[5];
    const float* rWh  = (const float*)d_in[6];
    const float* rbv  = (const float*)d_in[7];
    const float* wxv  = (const float*)d_in[8];
    const float* Whm  = (const float*)d_in[9];
    const float* bbv  = (const float*)d_in[10];
    const float* Vv   = (const float*)d_in[11];
    const float* cv   = (const float*)d_in[12];
    float* out = (float*)d_out;
    float* ws  = (float*)d_ws;

    hipFuncSetAttribute((const void*)gru_kernel,
                        hipFuncAttributeMaxDynamicSharedMemorySize, SMEM_BYTES);

    void* args[] = { &xseq, &uWx, &uWh, &ubv, &rWx, &rWh, &rbv,
                     &wxv, &Whm, &bbv, &Vv, &cv, &out, &ws };
    hipLaunchCooperativeKernel((void*)gru_kernel, dim3(NBLK), dim3(NTHR),
                               args, SMEM_BYTES, stream);
}

// Round 4
// 26930.698 us; speedup vs baseline: 4.6652x; 2.5206x over previous
//
#include <hip/hip_runtime.h>
#include <hip/hip_cooperative_groups.h>
#include <hip/hip_fp16.h>
#include <math.h>

namespace cg = cooperative_groups;

#define H      4096
#define SEQ    2048
#define HOR    64
#define NBLK   256
#define NTHR   512
#define NWAVE  (NTHR / 64)
#define RPW    2            // rows per wave; 8 waves * 2 = 16 rows per block
#define J      16           // float4 chunks per lane per row: H/(64*4)

#define SMEM_H     (H * 4)               // 16384 B: h vector (fp32)
#define SMEM_R     (NWAVE * RPW * H * 2) // 131072 B: r_Wh rows (fp16)
#define SMEM_RED   64
#define SMEM_BYTES (SMEM_H + SMEM_R + SMEM_RED)

// ---- fence-free L3-coherent point ops (sc0 sc1 = bypass L1+L2, served by
// memory-side Infinity Cache which is coherent across XCDs). No buffer_inv /
// buffer_wbl2 is ever emitted -> no per-poll L2 invalidate storms. ----
__device__ __forceinline__ void store_l3_f32(float* p, float v) {
    asm volatile("global_store_dword %0, %1, off sc0 sc1"
                 :: "v"(p), "v"(v) : "memory");
}
__device__ __forceinline__ void store_l3_i32(int* p, int v) {
    asm volatile("global_store_dword %0, %1, off sc0 sc1"
                 :: "v"(p), "v"(v) : "memory");
}
__device__ __forceinline__ int load_l3_i32(const int* p) {
    int v;
    asm volatile("global_load_dword %0, %1, off sc0 sc1\n\t"
                 "s_waitcnt vmcnt(0)"
                 : "=v"(v) : "v"(p) : "memory");
    return v;
}
__device__ __forceinline__ float4 load_l3_f4(const float4* p) {
    float4 v;
    asm volatile("global_load_dwordx4 %0, %1, off sc0 sc1"
                 : "=v"(v) : "v"(p) : "memory");
    return v;
}
__device__ __forceinline__ void vm_drain() {
    asm volatile("s_waitcnt vmcnt(0)" ::: "memory");
}

__device__ __forceinline__ float wave_reduce(float v) {
#pragma unroll
    for (int o = 32; o > 0; o >>= 1) v += __shfl_xor(v, o, 64);
    return v;
}

__device__ __forceinline__ float dot4(float4 a, float4 b) {
    float s = a.x * b.x;
    s = fmaf(a.y, b.y, s);
    s = fmaf(a.z, b.z, s);
    s = fmaf(a.w, b.w, s);
    return s;
}

union H4U { uint2 u; __half h[4]; };

__device__ __forceinline__ uint2 pack4(float4 v) {
    H4U c;
    c.h[0] = __float2half_rn(v.x); c.h[1] = __float2half_rn(v.y);
    c.h[2] = __float2half_rn(v.z); c.h[3] = __float2half_rn(v.w);
    return c.u;
}

__device__ __forceinline__ float4 unpack4(uint2 p) {
    H4U c; c.u = p;
    return make_float4(__half2float(c.h[0]), __half2float(c.h[1]),
                       __half2float(c.h[2]), __half2float(c.h[3]));
}

// Fully weight-resident persistent GRU, fence-free L3 flag barrier.
// 256 blocks x 512 threads, 1 block/CU. Block b owns rows [16b, 16b+16).
// Residency: Wh fp32 + u_Wh fp16 in VGPRs/AGPRs, r_Wh fp16 in LDS (128 KB).
// Per step: h exchange (16 KB) through L3 via sc0sc1 ops; per-block flag
// release (plain store after __syncthreads' vmcnt(0) drain); 256 threads
// each poll ONE flag with fence-free sc0sc1 loads.
__global__ __launch_bounds__(NTHR, 2) void gru_kernel(
    const float* __restrict__ xseq,
    const float* __restrict__ uWx, const float* __restrict__ uWh, const float* __restrict__ ubv,
    const float* __restrict__ rWx, const float* __restrict__ rWh, const float* __restrict__ rbv,
    const float* __restrict__ wxv, const float* __restrict__ Whm, const float* __restrict__ bbv,
    const float* __restrict__ Vv,  const float* __restrict__ cv,
    float* __restrict__ out, float* __restrict__ ws)
{
    cg::grid_group grid = cg::this_grid();
    extern __shared__ unsigned char smem[];
    float* hF  = (float*)smem;                         // h, 4096 fp32
    uint2* rW  = (uint2*)(smem + SMEM_H);              // r_Wh fp16
    float* red = (float*)(smem + SMEM_H + SMEM_R);     // NWAVE partials

    const int tid  = threadIdx.x;
    const int wv   = tid >> 6;
    const int lane = tid & 63;
    const int bid  = blockIdx.x;
    const int r0   = bid * (NWAVE * RPW) + wv * RPW;
    const int r1   = r0 + 1;

    float* hA = ws;
    float* hB = ws + H;
    int*   flags = (int*)(ws + 2 * H);   // poisoned 0xAAAAAAAA = negative -> no init needed

    // ---- one-time load: pin weights on-chip ----
    const float4* w0p = (const float4*)(Whm + (size_t)r0 * H);
    const float4* w1p = (const float4*)(Whm + (size_t)r1 * H);
    const float4* u0p = (const float4*)(uWh + (size_t)r0 * H);
    const float4* u1p = (const float4*)(uWh + (size_t)r1 * H);
    const float4* p0p = (const float4*)(rWh + (size_t)r0 * H);
    const float4* p1p = (const float4*)(rWh + (size_t)r1 * H);

    float4 wA[J], wB[J];
    uint2  uA[J], uB[J];
    uint2* rs0 = rW + (wv * RPW + 0) * (H / 4);
    uint2* rs1 = rW + (wv * RPW + 1) * (H / 4);

#pragma unroll
    for (int j = 0; j < J; ++j) {
        const int idx = j * 64 + lane;
        wA[j] = w0p[idx];
        wB[j] = w1p[idx];
        uA[j] = pack4(u0p[idx]);
        uB[j] = pack4(u1p[idx]);
        rs0[idx] = pack4(p0p[idx]);
        rs1[idx] = pack4(p1p[idx]);
    }
#pragma unroll
    for (int j = 0; j < J; ++j) {
        asm volatile("" : "+v"(wA[j].x), "+v"(wA[j].y), "+v"(wA[j].z), "+v"(wA[j].w));
        asm volatile("" : "+v"(wB[j].x), "+v"(wB[j].y), "+v"(wB[j].z), "+v"(wB[j].w));
        asm volatile("" : "+v"(uA[j].x), "+v"(uA[j].y));
        asm volatile("" : "+v"(uB[j].x), "+v"(uB[j].y));
    }

    const float uwx0 = uWx[r0], uwx1 = uWx[r1], ub0 = ubv[r0], ub1 = ubv[r1];
    const float rwx0 = rWx[r0], rwx1 = rWx[r1], rb0 = rbv[r0], rb1 = rbv[r1];
    const float wx0  = wxv[r0], wx1  = wxv[r1], bb0 = bbv[r0], bb1 = bbv[r1];
    const float c0 = cv[0];

    // h0 = 0: each block writes its own 16 entries straight to L3 (sc0 sc1),
    // so consumers' L3-direct loads at t=0 cannot see stale data.
    if (tid < NWAVE * RPW) store_l3_f32(&hA[bid * (NWAVE * RPW) + tid], 0.f);

    grid.sync();   // one-time; its release includes a vmcnt(0) drain

    const float4* v4g = (const float4*)Vv;

#pragma unroll 1
    for (int t = 0; t < SEQ + HOR; ++t) {
        // ---- fast grid barrier: wait until all blocks published h_t ----
        if (t > 0) {
            if (tid < NBLK) {
                while (load_l3_i32(&flags[tid]) < t)
                    __builtin_amdgcn_s_sleep(1);
            }
            __syncthreads();
        }

        // ---- pull h_t from L3 into LDS (2 x dwordx4 per thread, pipelined) ----
        const float4* hin4 = (const float4*)((t & 1) ? hB : hA);
        float* hout = (t & 1) ? hA : hB;
        float4 s0 = load_l3_f4(&hin4[tid]);
        float4 s1 = load_l3_f4(&hin4[tid + NTHR]);
        vm_drain();
        ((float4*)hF)[tid]        = s0;
        ((float4*)hF)[tid + NTHR] = s1;
        __syncthreads();

        float x;
        if (t < SEQ) {
            x = xseq[t];
        } else {
            // y = v.h + c0, redundantly and identically in every block
            float4 a0 = ((const float4*)hF)[tid];
            float4 a1 = ((const float4*)hF)[tid + NTHR];
            float p = dot4(a0, v4g[tid]) + dot4(a1, v4g[tid + NTHR]);
            p = wave_reduce(p);
            if (lane == 0) red[wv] = p;
            __syncthreads();
            float y = c0;
#pragma unroll
            for (int w = 0; w < NWAVE; ++w) y += red[w];
            x = y;
            if (t > SEQ && bid == 0 && tid == 0) out[t - SEQ - 1] = y;
        }

        // ---- six resident row-dots against LDS h ----
        float au0 = 0.f, au1 = 0.f, ar0 = 0.f, ar1 = 0.f, aw0 = 0.f, aw1 = 0.f;
#pragma unroll
        for (int j = 0; j < J; ++j) {
            const int idx = j * 64 + lane;
            const float4 hv = ((const float4*)hF)[idx];
            aw0 = fmaf(wA[j].x, hv.x, aw0); aw0 = fmaf(wA[j].y, hv.y, aw0);
            aw0 = fmaf(wA[j].z, hv.z, aw0); aw0 = fmaf(wA[j].w, hv.w, aw0);
            aw1 = fmaf(wB[j].x, hv.x, aw1); aw1 = fmaf(wB[j].y, hv.y, aw1);
            aw1 = fmaf(wB[j].z, hv.z, aw1); aw1 = fmaf(wB[j].w, hv.w, aw1);
            const float4 ua = unpack4(uA[j]);
            au0 = fmaf(ua.x, hv.x, au0); au0 = fmaf(ua.y, hv.y, au0);
            au0 = fmaf(ua.z, hv.z, au0); au0 = fmaf(ua.w, hv.w, au0);
            const float4 ub = unpack4(uB[j]);
            au1 = fmaf(ub.x, hv.x, au1); au1 = fmaf(ub.y, hv.y, au1);
            au1 = fmaf(ub.z, hv.z, au1); au1 = fmaf(ub.w, hv.w, au1);
            const float4 ra = unpack4(rs0[idx]);
            ar0 = fmaf(ra.x, hv.x, ar0); ar0 = fmaf(ra.y, hv.y, ar0);
            ar0 = fmaf(ra.z, hv.z, ar0); ar0 = fmaf(ra.w, hv.w, ar0);
            const float4 rb = unpack4(rs1[idx]);
            ar1 = fmaf(rb.x, hv.x, ar1); ar1 = fmaf(rb.y, hv.y, ar1);
            ar1 = fmaf(rb.z, hv.z, ar1); ar1 = fmaf(rb.w, hv.w, ar1);
        }
        au0 = wave_reduce(au0); au1 = wave_reduce(au1);
        ar0 = wave_reduce(ar0); ar1 = wave_reduce(ar1);
        aw0 = wave_reduce(aw0); aw1 = wave_reduce(aw1);

        if (lane == 0) {
            const float ho0 = hF[r0], ho1 = hF[r1];
            const float zu0 = fmaf(uwx0, x, au0 + ub0);
            const float zr0 = fmaf(rwx0, x, ar0 + rb0);
            const float u0  = 1.f / (1.f + expf(-zu0));
            const float g0  = 1.f / (1.f + expf(-zr0));
            const float hh0 = tanhf(fmaf(wx0, x, fmaf(g0, aw0, bb0)));
            store_l3_f32(&hout[r0], fmaf(u0, hh0 - ho0, ho0));
            const float zu1 = fmaf(uwx1, x, au1 + ub1);
            const float zr1 = fmaf(rwx1, x, ar1 + rb1);
            const float u1  = 1.f / (1.f + expf(-zu1));
            const float g1  = 1.f / (1.f + expf(-zr1));
            const float hh1 = tanhf(fmaf(wx1, x, fmaf(g1, aw1, bb1)));
            store_l3_f32(&hout[r1], fmaf(u1, hh1 - ho1, ho1));
        }

        // publish: __syncthreads() emits s_waitcnt vmcnt(0) per wave before
        // s_barrier -> every wave's h stores have reached L3. Then one flag store.
        __syncthreads();
        if (tid == 0)
            store_l3_i32(&flags[bid], t + 1);
    }

    // preds[63] from final h (SEQ+HOR even -> hA); block 0 must see all blocks
    if (bid == 0) {
        if (tid < NBLK) {
            while (load_l3_i32(&flags[tid]) < SEQ + HOR)
                __builtin_amdgcn_s_sleep(1);
        }
        __syncthreads();
        float4 s0 = load_l3_f4(&((const float4*)hA)[tid]);
        float4 s1 = load_l3_f4(&((const float4*)hA)[tid + NTHR]);
        vm_drain();
        ((float4*)hF)[tid]        = s0;
        ((float4*)hF)[tid + NTHR] = s1;
        __syncthreads();
        float4 a0 = ((const float4*)hF)[tid];
        float4 a1 = ((const float4*)hF)[tid + NTHR];
        float p = dot4(a0, v4g[tid]) + dot4(a1, v4g[tid + NTHR]);
        p = wave_reduce(p);
        if (lane == 0) red[wv] = p;
        __syncthreads();
        if (tid == 0) {
            float y = c0;
            for (int w = 0; w < NWAVE; ++w) y += red[w];
            out[HOR - 1] = y;
        }
    }
}

extern "C" void kernel_launch(void* const* d_in, const int* in_sizes, int n_in,
                              void* d_out, int out_size, void* d_ws, size_t ws_size,
                              hipStream_t stream) {
    const float* xseq = (const float*)d_in[0];
    const float* uWx  = (const float*)d_in[2];
    const float* uWh  = (const float*)d_in[3];
    const float* ubv  = (const float*)d_in[4];
    const float* rWx  = (const float*)d_in[5];
    const float* rWh  = (const float*)d_in[6];
    const float* rbv  = (const float*)d_in[7];
    const float* wxv  = (const float*)d_in[8];
    const float* Whm  = (const float*)d_in[9];
    const float* bbv  = (const float*)d_in[10];
    const float* Vv   = (const float*)d_in[11];
    const float* cv   = (const float*)d_in[12];
    float* out = (float*)d_out;
    float* ws  = (float*)d_ws;

    hipFuncSetAttribute((const void*)gru_kernel,
                        hipFuncAttributeMaxDynamicSharedMemorySize, SMEM_BYTES);

    void* args[] = { &xseq, &uWx, &uWh, &ubv, &rWx, &rWh, &rbv,
                     &wxv, &Whm, &bbv, &Vv, &cv, &out, &ws };
    hipLaunchCooperativeKernel((void*)gru_kernel, dim3(NBLK), dim3(NTHR),
                               args, SMEM_BYTES, stream);
}